// Round 9
// baseline (191.042 us; speedup 1.0000x reference)
//
#include <hip/hip_runtime.h>
#include <cfloat>
#include <cmath>

// Problem constants (fixed by the reference setup).
#define BB 64
#define NN 32768
#define CC 2
#define KK 10
#define S_SL 32                // slices of N -> 64 candidate slots/row, 1 per lane
#define SLICE (NN / S_SL)      // 1024 columns per slice
#define WPB 4                  // waves per block; each wave scans one slice
#define TPB 256
#define NBLK_PER_B (S_SL / WPB)   // 8 blocks per batch
#define VLARGE 1.0e6
#define KEY_MAX 0xFFFFFFFFFFFFFFFFull
#define BND_MARGIN 1.0e-3      // covers f32 nomination error vs f64 decisions (~2e-5)

__device__ __forceinline__ double dsig(float x) { return 1.0 / (1.0 + exp(-(double)x)); }
__device__ __forceinline__ double dsoftplus(double x) {
    return fmax(x, 0.0) + log1p(exp(-fabs(x)));
}
// clamped cost >= 0, so f32 bits are monotone as u32 -> (cost, col) packs sortable.
__device__ __forceinline__ unsigned long long packkey(float v, int c) {
    return ((unsigned long long)__float_as_uint(v) << 32) | (unsigned int)c;
}
__device__ __forceinline__ void merge2(unsigned long long& a1, unsigned long long& a2,
                                       unsigned long long b1, unsigned long long b2) {
    unsigned long long lo = a1 < b1 ? a1 : b1;
    unsigned long long hi = a1 < b1 ? b1 : a1;
    unsigned long long mb = a2 < b2 ? a2 : b2;
    a2 = hi < mb ? hi : mb;
    a1 = lo;
}
// Shared f32 column terms + row cost — IDENTICAL codegen in scan and rescan,
// so the slice-2nd bound is consistent between the two. Presence is folded
// into ck (absent: ck += VLARGE) — absent-row nominations are arbitrary but
// never affect valid picks (absent rows only get picked when no present row
// remains; those picks are pvalid=0 and consume nothing that matters).
__device__ __forceinline__ void colterms(float sraw, float eraw, float q0raw, float q1raw,
                                         float& s, float& e, float& u0, float& u1) {
    s = __fdividef(1.0f, 1.0f + __expf(-sraw));
    e = __fdividef(1.0f, 1.0f + __expf(-eraw));
    const float q0 = __fdividef(1.0f, 1.0f + __expf(-q0raw));
    const float q1 = __fdividef(1.0f, 1.0f + __expf(-q1raw));
    const float se2 = fmaf(s, s, e * e);
    const float t0 = q0 - 1.0f, t1 = q1 - 1.0f;
    u0 = se2 + fmaf(t0, t0, q1 * q1);   // class-0 full cost, minus row terms
    u1 = se2 + fmaf(t1, t1, q0 * q0);   // class-1
}
__device__ __forceinline__ float rowcost(float s, float e, float u0, float u1,
                                         float m0, float m1, float ckv, int cls) {
    float c = fmaf(m0, s, fmaf(m1, e, ((cls == 0) ? u0 : u1) + ckv));
    return fmaxf(c, 0.0f);              // rearrangement can go ~-2e-6; keep bits sortable
}
// f64 exact cost — decisions match numpy reference (verified r1/r3/r4/r6/r7/r8: absmax 0).
__device__ __forceinline__ double eval64(const float* ps, const float* pe, const float* pc,
                                         double fs, double fe, int cls, int pres, int col) {
    if (!pres) return VLARGE;
    const double s  = dsig(ps[col]);
    const double e  = dsig(pe[col]);
    const double q0 = dsig(pc[2 * col]);
    const double q1 = dsig(pc[2 * col + 1]);
    const double d0 = s - fs, d1 = e - fe;
    const double sc = (cls == 0) ? q0 : q1;
    return d0 * d0 + d1 * d1 + (q0 * q0 + q1 * q1 - 2.0 * sc + 1.0);
}

// ---------------- Fused kernel: scan (4 slices/block) + per-batch match + final reduce -------
__global__ __launch_bounds__(TPB)
void fused_kernel(const float* __restrict__ p_start, const float* __restrict__ p_end,
                  const float* __restrict__ p_cls, const float* __restrict__ p_conf,
                  const float* __restrict__ gt, ulonglong2* __restrict__ cand,
                  double* __restrict__ partials, unsigned int* __restrict__ batch_cnt,
                  unsigned int* __restrict__ counter, float* __restrict__ out, int out_size) {
    const int sx = blockIdx.x, b = blockIdx.y;
    const int tid = threadIdx.x, wv = tid >> 6, lane = tid & 63;
    const int sl = sx * WPB + wv;          // this wave's slice
    const float* ps  = p_start + (size_t)b * NN;
    const float* pe  = p_end   + (size_t)b * NN;
    const float* pc  = p_cls   + (size_t)b * NN * CC;
    const float* pcf = p_conf  + (size_t)b * NN;
    const float2* ps2 = (const float2*)ps;
    const float2* pe2 = (const float2*)pe;
    const float4* pc4 = (const float4*)pc;

    __shared__ double l_cost[KK][64];
    __shared__ int    l_col[KK][64];
    __shared__ double l_bnd[KK][S_SL];
    __shared__ double gfs[KK], gfe[KK];
    __shared__ int    gcls[KK], gpres[KK];
    __shared__ int    s_ticket;

    // ================= SCAN (r7 shape: 16 cols/lane, prefetch-all) =================
    // Prefetch all 24 vector loads before any compute (one vmcnt drain, not 8).
    float2 SV[8], EV[8]; float4 CV[8];
    #pragma unroll
    for (int it = 0; it < 8; it++) {
        const int pidx = sl * (SLICE / 2) + it * 64 + lane;
        SV[it] = ps2[pidx]; EV[it] = pe2[pidx]; CV[it] = pc4[pidx];
    }

    float m0[KK], m1[KK], ck[KK]; int rcl[KK];
    #pragma unroll
    for (int k = 0; k < KK; k++) {
        float f0 = gt[((size_t)b * KK + k) * 3 + 0];
        float f1 = gt[((size_t)b * KK + k) * 3 + 1];
        float f2 = gt[((size_t)b * KK + k) * 3 + 2];
        int pres = !(isnan(f0) || isnan(f1) || isnan(f2));
        if (isnan(f0)) f0 = 0.0f;
        if (isnan(f1)) f1 = 0.0f;
        if (isnan(f2)) f2 = 0.0f;
        int ci = (int)f2; ci = ci < 0 ? 0 : (ci > CC - 1 ? CC - 1 : ci);
        m0[k] = -2.0f * f0; m1[k] = -2.0f * f1;
        ck[k] = fmaf(f0, f0, f1 * f1) + (pres ? 0.0f : (float)VLARGE);
        rcl[k] = ci;
    }

    float v1[KK], v2[KK]; int c1[KK], c2[KK];
    #pragma unroll
    for (int k = 0; k < KK; k++) { v1[k] = FLT_MAX; v2[k] = FLT_MAX; c1[k] = 0x7fffffff; c2[k] = 0x7fffffff; }

    #pragma unroll
    for (int it = 0; it < 8; it++) {
        #pragma unroll
        for (int h = 0; h < 2; h++) {
            const int n = 2 * (sl * (SLICE / 2) + it * 64 + lane) + h;
            float s, e, u0, u1;
            colterms(h ? SV[it].y : SV[it].x, h ? EV[it].y : EV[it].x,
                     h ? CV[it].z : CV[it].x, h ? CV[it].w : CV[it].y, s, e, u0, u1);
            #pragma unroll
            for (int k = 0; k < KK; k++) {
                const float cost = rowcost(s, e, u0, u1, m0[k], m1[k], ck[k], rcl[k]);
                // n ascends per lane -> strict < keeps lowest col on ties
                const bool lt1 = cost < v1[k], lt2 = cost < v2[k];
                v2[k] = lt2 ? (lt1 ? v1[k] : cost) : v2[k];
                c2[k] = lt2 ? (lt1 ? c1[k] : n)    : c2[k];
                v1[k] = lt1 ? cost : v1[k];
                c1[k] = lt1 ? n    : c1[k];
            }
        }
    }

    unsigned long long k1[KK], k2[KK];
    #pragma unroll
    for (int k = 0; k < KK; k++) { k1[k] = packkey(v1[k], c1[k]); k2[k] = packkey(v2[k], c2[k]); }
    #pragma unroll
    for (int off = 1; off < 64; off <<= 1) {
        #pragma unroll
        for (int k = 0; k < KK; k++) {
            unsigned long long o1 = __shfl_xor(k1[k], off, 64);
            unsigned long long o2 = __shfl_xor(k2[k], off, 64);
            merge2(k1[k], k2[k], o1, o2);
        }
    }
    if (lane == 0) {
        #pragma unroll
        for (int k = 0; k < KK; k++) {
            ulonglong2 pk; pk.x = k1[k]; pk.y = k2[k];
            cand[((size_t)b * S_SL + sl) * KK + k] = pk;
        }
    }

    // ================= per-batch ticket: last of 8 blocks runs the match ===========
    __threadfence();                       // release this block's cand writes
    __syncthreads();
    if (tid == 0) s_ticket = (int)atomicAdd(&batch_cnt[b], 1u);
    __syncthreads();
    if (s_ticket != NBLK_PER_B - 1) return;
    __threadfence();                       // acquire other blocks' cand writes

    // ================= MATCH (r8-verified structure) ==============================
    if (tid < KK) {
        float f0 = gt[((size_t)b * KK + tid) * 3 + 0];
        float f1 = gt[((size_t)b * KK + tid) * 3 + 1];
        float f2 = gt[((size_t)b * KK + tid) * 3 + 2];
        int pres = !(isnan(f0) || isnan(f1) || isnan(f2));
        if (isnan(f0)) f0 = 0.0f;
        if (isnan(f1)) f1 = 0.0f;
        if (isnan(f2)) f2 = 0.0f;
        int ci = (int)f2; ci = ci < 0 ? 0 : (ci > CC - 1 ? CC - 1 : ci);
        gfs[tid] = (double)f0; gfe[tid] = (double)f1;
        gcls[tid] = ci; gpres[tid] = pres;
    }
    __syncthreads();

    // f64 eval of all K*64 candidates, 256 threads in parallel
    for (int idx = tid; idx < KK * 64; idx += TPB) {
        const int r = idx >> 6, jj = idx & 63, sli = jj >> 1;
        ulonglong2 pk = cand[((size_t)b * S_SL + sli) * KK + r];
        const unsigned long long key = (jj & 1) ? pk.y : pk.x;
        int c = (int)(unsigned int)(key & 0xffffffffull);
        if (c < 0 || c >= NN) c = 0;   // cannot trigger; OOB-crash guard only
        l_cost[r][jj] = eval64(ps, pe, pc, gfs[r], gfe[r], gcls[r], gpres[r], c);
        l_col[r][jj]  = c;
        if (jj & 1)
            l_bnd[r][sli] = (double)__uint_as_float((unsigned int)(key >> 32)) - BND_MARGIN;
    }
    __syncthreads();
    if (wv != 0) return;   // wave 0 owns the greedy (LDS persists)

    const int j = lane;
    const int s_my = j >> 1;
    double val[KK]; int col[KK]; double bnd[KK];
    #pragma unroll
    for (int r = 0; r < KK; r++) {
        val[r] = l_cost[r][j]; col[r] = l_col[r][j]; bnd[r] = l_bnd[r][s_my];
    }

    unsigned act = (1u << KK) - 1;
    int cons[KK], prow[KK], pcolv[KK], pvalid[KK];
    #pragma unroll
    for (int r = 0; r < KK; r++) { cons[r] = -1; pvalid[r] = 0; prow[r] = 0; pcolv[r] = 0; }

    for (int step = 0; step < KK; step++) {
        double bv = DBL_MAX; int brow = 0x7fffffff, bcol = 0x7fffffff;
        // guard: each rescan permanently realifies a slice; terminates provably.
        for (int guard = 0; guard < 64; guard++) {
            double lv = DBL_MAX; int lr = 0x7fffffff, lc = 0x7fffffff;
            #pragma unroll
            for (int r = 0; r < KK; r++) {
                if (!((act >> r) & 1)) continue;
                const int pcold = __shfl(col[r], j ^ 1, 64);
                const bool mine  = (col[r] >= 0);
                const bool bound = !mine && (pcold < 0) && ((j & 1) == 0);
                const double v = mine ? val[r] : (bound ? bnd[r] : DBL_MAX);
                const int    c = mine ? col[r] : (bound ? (-2 - s_my) : 0x7fffffff);
                if (v < lv || (v == lv && (r < lr || (r == lr && c < lc)))) {
                    lv = v; lr = r; lc = c;
                }
            }
            #pragma unroll
            for (int off = 1; off < 64; off <<= 1) {
                const double ov = __shfl_xor(lv, off, 64);
                const int   orr = __shfl_xor(lr, off, 64);
                const int   oc  = __shfl_xor(lc, off, 64);
                if (ov < lv || (ov == lv && (orr < lr || (orr == lr && oc < lc)))) {
                    lv = ov; lr = orr; lc = oc;
                }
            }
            bv = lv; brow = lr; bcol = lc;
            if (bcol >= 0 || bv == DBL_MAX) break;   // real winner (or nothing left)

            // a slice bound won -> exact top-2 rescan of (row brow, slice ss). Rare.
            const int ss = -2 - bcol;
            const float ffs = (float)gfs[brow], ffe = (float)gfe[brow];
            const int   cb  = gcls[brow], pb = gpres[brow];
            const float m0b = -2.0f * ffs, m1b = -2.0f * ffe;
            const float ckb = fmaf(ffs, ffs, ffe * ffe) + (pb ? 0.0f : (float)VLARGE);
            unsigned long long r1 = KEY_MAX, r2 = KEY_MAX;
            const int cbase = ss * SLICE;
            for (int t = j; t < SLICE; t += 64) {
                const int n = cbase + t;
                bool used = false;
                #pragma unroll
                for (int u = 0; u < KK; u++) used |= (cons[u] == n);
                float s, e, u0, u1;
                colterms(ps[n], pe[n], pc[2 * n], pc[2 * n + 1], s, e, u0, u1);
                const float cst = rowcost(s, e, u0, u1, m0b, m1b, ckb, cb);
                const unsigned long long kk = used ? KEY_MAX : packkey(cst, n);
                if (kk < r2) { if (kk < r1) { r2 = r1; r1 = kk; } else { r2 = kk; } }
            }
            #pragma unroll
            for (int off = 1; off < 64; off <<= 1) {
                const unsigned long long o1 = __shfl_xor(r1, off, 64);
                const unsigned long long o2 = __shfl_xor(r2, off, 64);
                merge2(r1, r2, o1, o2);
            }
            int cA = (int)(unsigned int)(r1 & 0xffffffffull);
            int cB = (int)(unsigned int)(r2 & 0xffffffffull);
            if (cA < 0 || cA >= NN) cA = 0;
            if (cB < 0 || cB >= NN) cB = 0;
            const double vA = (r1 == KEY_MAX) ? DBL_MAX
                : eval64(ps, pe, pc, gfs[brow], gfe[brow], cb, pb, cA);
            const double vB = (r2 == KEY_MAX) ? DBL_MAX
                : eval64(ps, pe, pc, gfs[brow], gfe[brow], cb, pb, cB);
            const double nb = (r2 == KEY_MAX) ? DBL_MAX
                : (double)__uint_as_float((unsigned int)(r2 >> 32)) - BND_MARGIN;
            #pragma unroll
            for (int r = 0; r < KK; r++) {
                if (r != brow) continue;
                if (j == 2 * ss)     { val[r] = vA; col[r] = (r1 == KEY_MAX) ? -1 : cA; }
                if (j == 2 * ss + 1) { val[r] = vB; col[r] = (r2 == KEY_MAX) ? -1 : cB; }
                if (s_my == ss) bnd[r] = nb;   // hidden >= rescan 2nd - margin
            }
        }

        prow[step]   = brow;
        pcolv[step]  = bcol;
        pvalid[step] = (bv < VLARGE * 0.5) && (bcol >= 0) && (brow < KK);
        cons[step]   = (bcol >= 0) ? bcol : -1;
        if (brow < KK) act &= ~(1u << brow);
        else break;                          // nothing left at all

        if (bcol >= 0) {
            #pragma unroll
            for (int r = 0; r < KK; r++)
                if (col[r] == bcol) col[r] = -1;
        }
    }

    // losses, one pick per lane
    double loss = 0.0, m = 0.0;
    if (j < KK && pvalid[j]) {
        const int r = prow[j], cidx = pcolv[j];
        const double ss = dsig(ps[cidx]);
        const double se = dsig(pe[cidx]);
        const double gs = gfs[r], ge = gfe[r];
        const double d0 = ss - gs, d1 = se - ge;
        double acc = d0 * d0 + d1 * d1;

        const double l0 = (double)pc[2 * cidx];
        const double l1 = (double)pc[2 * cidx + 1];
        const double y0 = (gcls[r] == 0) ? 1.0 : 0.0;
        const double y1 = 1.0 - y0;
        acc += y0 * dsoftplus(-l0) + (1.0 - y0) * dsoftplus(l0)
             + y1 * dsoftplus(-l1) + (1.0 - y1) * dsoftplus(l1);

        const double a1 = fmin(ss, se), b1 = fmax(ss, se);
        const double a2 = fmin(gs, ge), b2 = fmax(gs, ge);
        const double inter = fmax(0.0, fmin(b1, b2) - fmax(a1, a2));
        const double uni   = fmax(1e-8, fmax(b1, b2) - fmin(a1, a2));
        const double iou   = inter / uni;
        const double dcf   = dsig(pcf[cidx]) - iou;
        acc += dcf * dcf;
        loss = acc; m = 1.0;
    }
    #pragma unroll
    for (int off = 1; off < 64; off <<= 1) {
        loss += __shfl_xor(loss, off, 64);
        m    += __shfl_xor(m, off, 64);
    }
    if (j == 0) { partials[b * 2 + 0] = loss; partials[b * 2 + 1] = m; }

    // fused finalize — last match-block reduces all partials
    __threadfence();
    int ticket = 0;
    if (j == 0) ticket = (int)atomicAdd(counter, 1u);
    ticket = __shfl(ticket, 0, 64);
    if (ticket == BB - 1) {
        __threadfence();
        for (int i = j; i < out_size; i += 64) out[i] = 0.0f;
        double s = partials[j * 2 + 0];
        double mm = partials[j * 2 + 1];
        #pragma unroll
        for (int off = 1; off < 64; off <<= 1) {
            s  += __shfl_xor(s, off, 64);
            mm += __shfl_xor(mm, off, 64);
        }
        if (j == 0) {
            const double total = s / (mm + 1e-8);
            out[0] = (float)(mm > 0.0 ? total : 0.0);
        }
    }
}

extern "C" void kernel_launch(void* const* d_in, const int* in_sizes, int n_in,
                              void* d_out, int out_size, void* d_ws, size_t ws_size,
                              hipStream_t stream) {
    const float* p_start = (const float*)d_in[0];  // (B, N)
    const float* p_end   = (const float*)d_in[1];  // (B, N)
    const float* p_cls   = (const float*)d_in[2];  // (B, N, C)
    const float* p_conf  = (const float*)d_in[3];  // (B, N)
    const float* gt      = (const float*)d_in[4];  // (B, K, 3)

    const size_t cand_bytes = (size_t)BB * S_SL * KK * sizeof(ulonglong2);   // 320 KiB
    const size_t part_bytes = (size_t)BB * 2 * sizeof(double);               // 1 KiB
    ulonglong2*   cand      = (ulonglong2*)d_ws;
    double*       partials  = (double*)((char*)d_ws + cand_bytes);
    unsigned int* batch_cnt = (unsigned int*)((char*)d_ws + cand_bytes + part_bytes);
    unsigned int* counter   = batch_cnt + BB;

    hipMemsetAsync(batch_cnt, 0, (BB + 1) * sizeof(unsigned int), stream);
    fused_kernel<<<dim3(NBLK_PER_B, BB), TPB, 0, stream>>>(
        p_start, p_end, p_cls, p_conf, gt, cand, partials, batch_cnt, counter,
        (float*)d_out, out_size);
}

// Round 10
// 144.364 us; speedup vs baseline: 1.3233x; 1.3233x over previous
//
#include <hip/hip_runtime.h>
#include <cfloat>
#include <cmath>

// Problem constants (fixed by the reference setup).
#define BB 64
#define NN 32768
#define CC 2
#define KK 10
#define S_SL 64                // slices of N -> lane j of the match wave owns slice j
#define SLICE (NN / S_SL)      // 512 columns per slice
#define TPM 256                // match kernel threads (4 waves; waves 1-3 only do eval)
#define VLARGE 1.0e6
#define KEY32_MAX 0xFFFFFFFFu
#define VMASK 0xFFFFFC00u      // f32 cost bits, low 10 dropped (floor) -> monotone u32
#define CMASK 0x3FFu           // in-slice column (0..511)
#define BND_MARGIN 1.0e-3      // covers f32 nomination + 10-bit floor vs f64 decisions

__device__ __forceinline__ double dsig(float x) { return 1.0 / (1.0 + exp(-(double)x)); }
__device__ __forceinline__ double dsoftplus(double x) {
    return fmax(x, 0.0) + log1p(exp(-fabs(x)));
}
__device__ __forceinline__ float rdfl_f(float x) {
    return __int_as_float(__builtin_amdgcn_readfirstlane(__float_as_int(x)));
}
// merge two sorted top-2 u32 key lists -> sorted top-2 in a1,a2
__device__ __forceinline__ void merge2_32(unsigned& a1, unsigned& a2,
                                          unsigned b1, unsigned b2) {
    unsigned lo = a1 < b1 ? a1 : b1;
    unsigned hi = a1 < b1 ? b1 : a1;
    unsigned mb = a2 < b2 ? a2 : b2;
    a2 = hi < mb ? hi : mb;
    a1 = lo;
}
// Shared f32 column terms + row cost — IDENTICAL codegen in scan and rescan,
// so the slice-2nd bound is consistent between the two. Presence folded into
// ck (absent: +VLARGE); this input set never has absent rows (no NaNs).
__device__ __forceinline__ void colterms(float sraw, float eraw, float q0raw, float q1raw,
                                         float& s, float& e, float& u0, float& u1) {
    s = __fdividef(1.0f, 1.0f + __expf(-sraw));
    e = __fdividef(1.0f, 1.0f + __expf(-eraw));
    const float q0 = __fdividef(1.0f, 1.0f + __expf(-q0raw));
    const float q1 = __fdividef(1.0f, 1.0f + __expf(-q1raw));
    const float se2 = fmaf(s, s, e * e);
    const float t0 = q0 - 1.0f, t1 = q1 - 1.0f;
    u0 = se2 + fmaf(t0, t0, q1 * q1);   // class-0 full cost, minus row terms
    u1 = se2 + fmaf(t1, t1, q0 * q0);   // class-1
}
__device__ __forceinline__ float rowcost(float s, float e, float u0, float u1,
                                         float m0, float m1, float ckv, int cls) {
    float c = fmaf(m0, s, fmaf(m1, e, ((cls == 0) ? u0 : u1) + ckv));
    return fmaxf(c, 0.0f);              // rearrangement can go ~-2e-6; keep bits sortable
}
// f64 exact cost — decisions match numpy reference (verified r1/r3/r4/r6/r7/r8: absmax 0).
__device__ __forceinline__ double eval64(const float* ps, const float* pe, const float* pc,
                                         double fs, double fe, int cls, int pres, int col) {
    if (!pres) return VLARGE;
    const double s  = dsig(ps[col]);
    const double e  = dsig(pe[col]);
    const double q0 = dsig(pc[2 * col]);
    const double q1 = dsig(pc[2 * col + 1]);
    const double d0 = s - fs, d1 = e - fe;
    const double sc = (cls == 0) ? q0 : q1;
    return d0 * d0 + d1 * d1 + (q0 * q0 + q1 * q1 - 2.0 * sc + 1.0);
}

// ---------------- Kernel A: one wave per (slice, batch); per-row top-2 per slice --------------
// u32 keys (floored f32 | in-slice col): halves the butterfly cost vs u64. 4096 blocks
// -> 4 waves/SIMD for latency hiding (r7 had 2).
__global__ __launch_bounds__(64)
void scan_kernel(const float* __restrict__ p_start, const float* __restrict__ p_end,
                 const float* __restrict__ p_cls, const float* __restrict__ gt,
                 uint2* __restrict__ cand) {
    const int sl = blockIdx.x, b = blockIdx.y, lane = threadIdx.x;
    const float2* ps2 = (const float2*)(p_start + (size_t)b * NN);
    const float2* pe2 = (const float2*)(p_end   + (size_t)b * NN);
    const float4* pc4 = (const float4*)(p_cls   + (size_t)b * NN * CC);

    // prefetch all 12 vector loads (one vmcnt drain; ~32 VGPRs of data)
    float2 SV[4], EV[4]; float4 CV[4];
    const int base2 = sl * (SLICE / 2);
    #pragma unroll
    for (int it = 0; it < 4; it++) {
        const int pidx = base2 + it * 64 + lane;
        SV[it] = ps2[pidx]; EV[it] = pe2[pidx]; CV[it] = pc4[pidx];
    }

    // row constants -> SGPRs (wave-uniform; frees VGPRs, SGPR operands in FMA)
    float m0[KK], m1[KK], ck[KK]; int rcl[KK];
    #pragma unroll
    for (int k = 0; k < KK; k++) {
        float f0 = gt[((size_t)b * KK + k) * 3 + 0];
        float f1 = gt[((size_t)b * KK + k) * 3 + 1];
        float f2 = gt[((size_t)b * KK + k) * 3 + 2];
        int pres = !(isnan(f0) || isnan(f1) || isnan(f2));
        if (isnan(f0)) f0 = 0.0f;
        if (isnan(f1)) f1 = 0.0f;
        if (isnan(f2)) f2 = 0.0f;
        int ci = (int)f2; ci = ci < 0 ? 0 : (ci > CC - 1 ? CC - 1 : ci);
        m0[k] = rdfl_f(-2.0f * f0);
        m1[k] = rdfl_f(-2.0f * f1);
        ck[k] = rdfl_f(fmaf(f0, f0, f1 * f1) + (pres ? 0.0f : (float)VLARGE));
        rcl[k] = __builtin_amdgcn_readfirstlane(ci);
    }

    unsigned k1[KK], k2[KK];
    #pragma unroll
    for (int k = 0; k < KK; k++) { k1[k] = KEY32_MAX; k2[k] = KEY32_MAX; }

    #pragma unroll
    for (int it = 0; it < 4; it++) {
        #pragma unroll
        for (int h = 0; h < 2; h++) {
            const unsigned colLocal = 2u * (it * 64 + lane) + h;   // 0..511, asc per lane
            float s, e, u0, u1;
            colterms(h ? SV[it].y : SV[it].x, h ? EV[it].y : EV[it].x,
                     h ? CV[it].z : CV[it].x, h ? CV[it].w : CV[it].y, s, e, u0, u1);
            #pragma unroll
            for (int k = 0; k < KK; k++) {
                const float cost = rowcost(s, e, u0, u1, m0[k], m1[k], ck[k], rcl[k]);
                const unsigned key = (__float_as_uint(cost) & VMASK) | colLocal;
                // strict < keeps lowest col on floored-value ties
                if (key < k2[k]) {
                    if (key < k1[k]) { k2[k] = k1[k]; k1[k] = key; }
                    else             { k2[k] = key; }
                }
            }
        }
    }

    #pragma unroll
    for (int off = 1; off < 64; off <<= 1) {
        #pragma unroll
        for (int k = 0; k < KK; k++) {
            const unsigned o1 = __shfl_xor(k1[k], off, 64);
            const unsigned o2 = __shfl_xor(k2[k], off, 64);
            merge2_32(k1[k], k2[k], o1, o2);
        }
    }
    // butterfly leaves the result in every lane; lanes 0..9 store their row
    #pragma unroll
    for (int k = 0; k < KK; k++) {
        if (lane == k) {
            uint2 pk; pk.x = k1[k]; pk.y = k2[k];
            cand[((size_t)b * S_SL + sl) * KK + k] = pk;
        }
    }
}

// ---------------- Kernel B: parallel f64 eval + lane-owns-slice greedy + fused finalize ------
__global__ __launch_bounds__(TPM)
void match_kernel(const float* __restrict__ p_start, const float* __restrict__ p_end,
                  const float* __restrict__ p_cls, const float* __restrict__ p_conf,
                  const float* __restrict__ gt, const uint2* __restrict__ cand,
                  double* __restrict__ partials, unsigned int* __restrict__ counter,
                  float* __restrict__ out, int out_size) {
    const int b = blockIdx.x, tid = threadIdx.x;
    const int j = tid & 63, wv = tid >> 6;
    const float* ps  = p_start + (size_t)b * NN;
    const float* pe  = p_end   + (size_t)b * NN;
    const float* pc  = p_cls   + (size_t)b * NN * CC;
    const float* pcf = p_conf  + (size_t)b * NN;

    __shared__ double l_cost[KK][2 * S_SL];   // 10 KiB
    __shared__ int    l_col[KK][2 * S_SL];
    __shared__ double l_bnd[KK][S_SL];
    __shared__ double gfs[KK], gfe[KK];
    __shared__ int    gcls[KK], gpres[KK];

    // ---- Phase 0: gt load + clean ----
    if (tid < KK) {
        float f0 = gt[((size_t)b * KK + tid) * 3 + 0];
        float f1 = gt[((size_t)b * KK + tid) * 3 + 1];
        float f2 = gt[((size_t)b * KK + tid) * 3 + 2];
        int pres = !(isnan(f0) || isnan(f1) || isnan(f2));
        if (isnan(f0)) f0 = 0.0f;
        if (isnan(f1)) f1 = 0.0f;
        if (isnan(f2)) f2 = 0.0f;
        int ci = (int)f2; ci = ci < 0 ? 0 : (ci > CC - 1 ? CC - 1 : ci);
        gfs[tid] = (double)f0; gfe[tid] = (double)f1;
        gcls[tid] = ci; gpres[tid] = pres;
    }
    __syncthreads();

    // ---- Phase 1: f64 eval of all K*128 candidates, 256 threads in parallel ----
    for (int idx = tid; idx < KK * 2 * S_SL; idx += TPM) {
        const int r = idx >> 7, jj = idx & 127, sl = jj >> 1;
        uint2 pk = cand[((size_t)b * S_SL + sl) * KK + r];
        const unsigned key = (jj & 1) ? pk.y : pk.x;
        int c = sl * SLICE + (int)(key & CMASK);
        if (c < 0 || c >= NN) c = 0;   // cannot trigger; OOB-crash guard only
        l_cost[r][jj] = eval64(ps, pe, pc, gfs[r], gfe[r], gcls[r], gpres[r], c);
        l_col[r][jj]  = c;
        if (jj & 1)
            l_bnd[r][sl] = (double)__uint_as_float(key & VMASK) - BND_MARGIN;
    }
    __syncthreads();
    if (wv != 0) return;   // wave 0 owns the greedy (LDS persists)

    // ---- Phase 2: greedy matching; lane j owns slice j entirely ----
    double v0[KK], v1v[KK], bnd[KK]; int c0[KK], c1v[KK];
    #pragma unroll
    for (int r = 0; r < KK; r++) {
        v0[r] = l_cost[r][2 * j];     c0[r]  = l_col[r][2 * j];
        v1v[r] = l_cost[r][2 * j + 1]; c1v[r] = l_col[r][2 * j + 1];
        bnd[r] = l_bnd[r][j];
    }

    unsigned act = (1u << KK) - 1;
    int cons[KK], prow[KK], pcolv[KK], pvalid[KK];
    #pragma unroll
    for (int r = 0; r < KK; r++) { cons[r] = -1; pvalid[r] = 0; prow[r] = 0; pcolv[r] = 0; }

    for (int step = 0; step < KK; step++) {
        double bv = DBL_MAX; int brow = 0x7fffffff, bcol = 0x7fffffff;
        // guard: each rescan permanently realifies a slice; terminates provably.
        for (int guard = 0; guard < 64; guard++) {
            double lv = DBL_MAX; int lr = 0x7fffffff, lc = 0x7fffffff;
            #pragma unroll
            for (int r = 0; r < KK; r++) {
                if (!((act >> r) & 1)) continue;
                const bool a0 = (c0[r] >= 0), a1 = (c1v[r] >= 0);
                double va = DBL_MAX; int ca = 0x7fffffff;
                if (a0) { va = v0[r]; ca = c0[r]; }
                if (a1 && (v1v[r] < va || (v1v[r] == va && c1v[r] < ca))) { va = v1v[r]; ca = c1v[r]; }
                if (!a0 && !a1 && bnd[r] < DBL_MAX) { va = bnd[r]; ca = -2 - j; }
                if (va < lv || (va == lv && (r < lr || (r == lr && ca < lc)))) {
                    lv = va; lr = r; lc = ca;
                }
            }
            #pragma unroll
            for (int off = 1; off < 64; off <<= 1) {
                const double ov = __shfl_xor(lv, off, 64);
                const int   orr = __shfl_xor(lr, off, 64);
                const int   oc  = __shfl_xor(lc, off, 64);
                if (ov < lv || (ov == lv && (orr < lr || (orr == lr && oc < lc)))) {
                    lv = ov; lr = orr; lc = oc;
                }
            }
            bv = lv; brow = lr; bcol = lc;
            if (bcol >= 0 || bv == DBL_MAX) break;   // real winner (or nothing left)

            // a slice bound won -> exact top-2 rescan of (row brow, slice ss). Rare.
            const int ss = -2 - bcol;
            const float ffs = (float)gfs[brow], ffe = (float)gfe[brow];
            const int   cb  = gcls[brow], pb = gpres[brow];
            const float m0b = -2.0f * ffs, m1b = -2.0f * ffe;
            const float ckb = fmaf(ffs, ffs, ffe * ffe) + (pb ? 0.0f : (float)VLARGE);
            unsigned q1 = KEY32_MAX, q2 = KEY32_MAX;
            const int cbase = ss * SLICE;
            for (int t = j; t < SLICE; t += 64) {
                const int n = cbase + t;
                bool used = false;
                #pragma unroll
                for (int u = 0; u < KK; u++) used |= (cons[u] == n);
                float s, e, u0, u1;
                colterms(ps[n], pe[n], pc[2 * n], pc[2 * n + 1], s, e, u0, u1);
                const float cst = rowcost(s, e, u0, u1, m0b, m1b, ckb, cb);
                const unsigned kk = used ? KEY32_MAX : ((__float_as_uint(cst) & VMASK) | (unsigned)t);
                if (kk < q2) { if (kk < q1) { q2 = q1; q1 = kk; } else { q2 = kk; } }
            }
            #pragma unroll
            for (int off = 1; off < 64; off <<= 1) {
                const unsigned o1 = __shfl_xor(q1, off, 64);
                const unsigned o2 = __shfl_xor(q2, off, 64);
                merge2_32(q1, q2, o1, o2);
            }
            int cA = cbase + (int)(q1 & CMASK);
            int cB = cbase + (int)(q2 & CMASK);
            if (cA < 0 || cA >= NN) cA = 0;
            if (cB < 0 || cB >= NN) cB = 0;
            const double vA = (q1 == KEY32_MAX) ? DBL_MAX
                : eval64(ps, pe, pc, gfs[brow], gfe[brow], cb, pb, cA);
            const double vB = (q2 == KEY32_MAX) ? DBL_MAX
                : eval64(ps, pe, pc, gfs[brow], gfe[brow], cb, pb, cB);
            const double nb = (q2 == KEY32_MAX) ? DBL_MAX
                : (double)__uint_as_float(q2 & VMASK) - BND_MARGIN;
            #pragma unroll
            for (int r = 0; r < KK; r++) {
                if (r != brow) continue;
                if (j == ss) {
                    v0[r]  = vA; c0[r]  = (q1 == KEY32_MAX) ? -1 : cA;
                    v1v[r] = vB; c1v[r] = (q2 == KEY32_MAX) ? -1 : cB;
                    bnd[r] = nb;   // hidden >= rescan 2nd - margin
                }
            }
        }

        prow[step]   = brow;
        pcolv[step]  = bcol;
        pvalid[step] = (bv < VLARGE * 0.5) && (bcol >= 0) && (brow < KK);
        cons[step]   = (bcol >= 0) ? bcol : -1;
        if (brow < KK) act &= ~(1u << brow);
        else break;                          // nothing left at all

        if (bcol >= 0) {
            #pragma unroll
            for (int r = 0; r < KK; r++) {
                if (c0[r] == bcol)  { c0[r] = -1;  v0[r]  = DBL_MAX; }
                if (c1v[r] == bcol) { c1v[r] = -1; v1v[r] = DBL_MAX; }
            }
        }
    }

    // ---- Phase 3: losses, one pick per lane ----
    double loss = 0.0, m = 0.0;
    if (j < KK && pvalid[j]) {
        const int r = prow[j], cidx = pcolv[j];
        const double ss = dsig(ps[cidx]);
        const double se = dsig(pe[cidx]);
        const double gs = gfs[r], ge = gfe[r];
        const double d0 = ss - gs, d1 = se - ge;
        double acc = d0 * d0 + d1 * d1;

        const double l0 = (double)pc[2 * cidx];
        const double l1 = (double)pc[2 * cidx + 1];
        const double y0 = (gcls[r] == 0) ? 1.0 : 0.0;
        const double y1 = 1.0 - y0;
        acc += y0 * dsoftplus(-l0) + (1.0 - y0) * dsoftplus(l0)
             + y1 * dsoftplus(-l1) + (1.0 - y1) * dsoftplus(l1);

        const double a1 = fmin(ss, se), b1 = fmax(ss, se);
        const double a2 = fmin(gs, ge), b2 = fmax(gs, ge);
        const double inter = fmax(0.0, fmin(b1, b2) - fmax(a1, a2));
        const double uni   = fmax(1e-8, fmax(b1, b2) - fmin(a1, a2));
        const double iou   = inter / uni;
        const double dcf   = dsig(pcf[cidx]) - iou;
        acc += dcf * dcf;
        loss = acc; m = 1.0;
    }
    #pragma unroll
    for (int off = 1; off < 64; off <<= 1) {
        loss += __shfl_xor(loss, off, 64);
        m    += __shfl_xor(m, off, 64);
    }
    if (j == 0) { partials[b * 2 + 0] = loss; partials[b * 2 + 1] = m; }

    // ---- Phase 4: fused finalize — last block reduces all partials (r8-validated) ----
    __threadfence();
    int ticket = 0;
    if (j == 0) ticket = (int)atomicAdd(counter, 1u);
    ticket = __shfl(ticket, 0, 64);
    if (ticket == BB - 1) {
        __threadfence();
        for (int i = j; i < out_size; i += 64) out[i] = 0.0f;
        double s = partials[j * 2 + 0];
        double mm = partials[j * 2 + 1];
        #pragma unroll
        for (int off = 1; off < 64; off <<= 1) {
            s  += __shfl_xor(s, off, 64);
            mm += __shfl_xor(mm, off, 64);
        }
        if (j == 0) {
            const double total = s / (mm + 1e-8);
            out[0] = (float)(mm > 0.0 ? total : 0.0);
        }
    }
}

extern "C" void kernel_launch(void* const* d_in, const int* in_sizes, int n_in,
                              void* d_out, int out_size, void* d_ws, size_t ws_size,
                              hipStream_t stream) {
    const float* p_start = (const float*)d_in[0];  // (B, N)
    const float* p_end   = (const float*)d_in[1];  // (B, N)
    const float* p_cls   = (const float*)d_in[2];  // (B, N, C)
    const float* p_conf  = (const float*)d_in[3];  // (B, N)
    const float* gt      = (const float*)d_in[4];  // (B, K, 3)

    const size_t cand_bytes = (size_t)BB * S_SL * KK * sizeof(uint2);   // 320 KiB
    const size_t part_bytes = (size_t)BB * 2 * sizeof(double);          // 1 KiB
    uint2*        cand     = (uint2*)d_ws;
    double*       partials = (double*)((char*)d_ws + cand_bytes);
    unsigned int* counter  = (unsigned int*)((char*)d_ws + cand_bytes + part_bytes);

    hipMemsetAsync(counter, 0, sizeof(unsigned int), stream);
    scan_kernel<<<dim3(S_SL, BB), 64, 0, stream>>>(p_start, p_end, p_cls, gt, cand);
    match_kernel<<<BB, TPM, 0, stream>>>(p_start, p_end, p_cls, p_conf, gt, cand,
                                         partials, counter, (float*)d_out, out_size);
}

// Round 11
// 141.794 us; speedup vs baseline: 1.3473x; 1.0181x over previous
//
#include <hip/hip_runtime.h>
#include <cfloat>
#include <cmath>

// Problem constants (fixed by the reference setup).
#define BB 64
#define NN 32768
#define CC 2
#define KK 10
#define S_SL 64                // slices of N -> lane j of the match wave owns slice j
#define SLICE (NN / S_SL)      // 512 columns per slice
#define TPM 256                // match kernel threads (4 waves; waves 1-3 only do eval)
#define VLARGE 1.0e6
#define KEY32_MAX 0xFFFFFFFFu
#define VMASK 0xFFFFFC00u      // f32 cost bits, low 10 dropped (floor) -> monotone u32
#define CMASK 0x3FFu           // in-slice column (0..511)
#define BND_MARGIN 1.0e-3      // covers f32 nomination + 10-bit floor vs f64 decisions

__device__ __forceinline__ double dsig(float x) { return 1.0 / (1.0 + exp(-(double)x)); }
__device__ __forceinline__ double dsoftplus(double x) {
    return fmax(x, 0.0) + log1p(exp(-fabs(x)));
}
__device__ __forceinline__ float rdfl_f(float x) {
    return __int_as_float(__builtin_amdgcn_readfirstlane(__float_as_int(x)));
}
// merge two sorted top-2 u32 key lists -> sorted top-2 in a1,a2
__device__ __forceinline__ void merge2_32(unsigned& a1, unsigned& a2,
                                          unsigned b1, unsigned b2) {
    unsigned lo = a1 < b1 ? a1 : b1;
    unsigned hi = a1 < b1 ? b1 : a1;
    unsigned mb = a2 < b2 ? a2 : b2;
    a2 = hi < mb ? hi : mb;
    a1 = lo;
}
// Shared f32 column terms + row cost — IDENTICAL codegen in scan and rescan,
// so the slice-2nd bound is consistent between the two.
__device__ __forceinline__ void colterms(float sraw, float eraw, float q0raw, float q1raw,
                                         float& s, float& e, float& u0, float& u1) {
    s = __fdividef(1.0f, 1.0f + __expf(-sraw));
    e = __fdividef(1.0f, 1.0f + __expf(-eraw));
    const float q0 = __fdividef(1.0f, 1.0f + __expf(-q0raw));
    const float q1 = __fdividef(1.0f, 1.0f + __expf(-q1raw));
    const float se2 = fmaf(s, s, e * e);
    const float t0 = q0 - 1.0f, t1 = q1 - 1.0f;
    u0 = se2 + fmaf(t0, t0, q1 * q1);   // class-0 full cost, minus row terms
    u1 = se2 + fmaf(t1, t1, q0 * q0);   // class-1
}
__device__ __forceinline__ float rowcost(float s, float e, float u0, float u1,
                                         float m0, float m1, float ckv, int cls) {
    float c = fmaf(m0, s, fmaf(m1, e, ((cls == 0) ? u0 : u1) + ckv));
    return fmaxf(c, 0.0f);              // rearrangement can go ~-2e-6; keep bits sortable
}
// f64 exact cost — decisions match numpy reference (verified r1/r3/r4/r6/r7/r8/r10: absmax 0).
__device__ __forceinline__ double eval64(const float* ps, const float* pe, const float* pc,
                                         double fs, double fe, int cls, int pres, int col) {
    if (!pres) return VLARGE;
    const double s  = dsig(ps[col]);
    const double e  = dsig(pe[col]);
    const double q0 = dsig(pc[2 * col]);
    const double q1 = dsig(pc[2 * col + 1]);
    const double d0 = s - fs, d1 = e - fe;
    const double sc = (cls == 0) ? q0 : q1;
    return d0 * d0 + d1 * d1 + (q0 * q0 + q1 * q1 - 2.0 * sc + 1.0);
}

// ---------------- Kernel A: one wave per (slice, batch); per-row top-2 per slice --------------
// (verbatim from r10 except: block (0,0) zeroes the match ticket counter)
__global__ __launch_bounds__(64)
void scan_kernel(const float* __restrict__ p_start, const float* __restrict__ p_end,
                 const float* __restrict__ p_cls, const float* __restrict__ gt,
                 uint2* __restrict__ cand, unsigned int* __restrict__ counter) {
    const int sl = blockIdx.x, b = blockIdx.y, lane = threadIdx.x;
    if (sl == 0 && b == 0 && lane == 0) *counter = 0;   // ordered before match by kernel boundary
    const float2* ps2 = (const float2*)(p_start + (size_t)b * NN);
    const float2* pe2 = (const float2*)(p_end   + (size_t)b * NN);
    const float4* pc4 = (const float4*)(p_cls   + (size_t)b * NN * CC);

    // prefetch all 12 vector loads (one vmcnt drain)
    float2 SV[4], EV[4]; float4 CV[4];
    const int base2 = sl * (SLICE / 2);
    #pragma unroll
    for (int it = 0; it < 4; it++) {
        const int pidx = base2 + it * 64 + lane;
        SV[it] = ps2[pidx]; EV[it] = pe2[pidx]; CV[it] = pc4[pidx];
    }

    // row constants -> SGPRs (wave-uniform)
    float m0[KK], m1[KK], ck[KK]; int rcl[KK];
    #pragma unroll
    for (int k = 0; k < KK; k++) {
        float f0 = gt[((size_t)b * KK + k) * 3 + 0];
        float f1 = gt[((size_t)b * KK + k) * 3 + 1];
        float f2 = gt[((size_t)b * KK + k) * 3 + 2];
        int pres = !(isnan(f0) || isnan(f1) || isnan(f2));
        if (isnan(f0)) f0 = 0.0f;
        if (isnan(f1)) f1 = 0.0f;
        if (isnan(f2)) f2 = 0.0f;
        int ci = (int)f2; ci = ci < 0 ? 0 : (ci > CC - 1 ? CC - 1 : ci);
        m0[k] = rdfl_f(-2.0f * f0);
        m1[k] = rdfl_f(-2.0f * f1);
        ck[k] = rdfl_f(fmaf(f0, f0, f1 * f1) + (pres ? 0.0f : (float)VLARGE));
        rcl[k] = __builtin_amdgcn_readfirstlane(ci);
    }

    unsigned k1[KK], k2[KK];
    #pragma unroll
    for (int k = 0; k < KK; k++) { k1[k] = KEY32_MAX; k2[k] = KEY32_MAX; }

    #pragma unroll
    for (int it = 0; it < 4; it++) {
        #pragma unroll
        for (int h = 0; h < 2; h++) {
            const unsigned colLocal = 2u * (it * 64 + lane) + h;   // 0..511, asc per lane
            float s, e, u0, u1;
            colterms(h ? SV[it].y : SV[it].x, h ? EV[it].y : EV[it].x,
                     h ? CV[it].z : CV[it].x, h ? CV[it].w : CV[it].y, s, e, u0, u1);
            #pragma unroll
            for (int k = 0; k < KK; k++) {
                const float cost = rowcost(s, e, u0, u1, m0[k], m1[k], ck[k], rcl[k]);
                const unsigned key = (__float_as_uint(cost) & VMASK) | colLocal;
                if (key < k2[k]) {
                    if (key < k1[k]) { k2[k] = k1[k]; k1[k] = key; }
                    else             { k2[k] = key; }
                }
            }
        }
    }

    #pragma unroll
    for (int off = 1; off < 64; off <<= 1) {
        #pragma unroll
        for (int k = 0; k < KK; k++) {
            const unsigned o1 = __shfl_xor(k1[k], off, 64);
            const unsigned o2 = __shfl_xor(k2[k], off, 64);
            merge2_32(k1[k], k2[k], o1, o2);
        }
    }
    #pragma unroll
    for (int k = 0; k < KK; k++) {
        if (lane == k) {
            uint2 pk; pk.x = k1[k]; pk.y = k2[k];
            cand[((size_t)b * S_SL + sl) * KK + k] = pk;
        }
    }
}

// ---------------- Kernel B: lazy-rank2 f64 eval + lane-owns-slice greedy + fused finalize ----
__global__ __launch_bounds__(TPM)
void match_kernel(const float* __restrict__ p_start, const float* __restrict__ p_end,
                  const float* __restrict__ p_cls, const float* __restrict__ p_conf,
                  const float* __restrict__ gt, const uint2* __restrict__ cand,
                  double* __restrict__ partials, unsigned int* __restrict__ counter,
                  float* __restrict__ out, int out_size) {
    const int b = blockIdx.x, tid = threadIdx.x;
    const int j = tid & 63, wv = tid >> 6;
    const float* ps  = p_start + (size_t)b * NN;
    const float* pe  = p_end   + (size_t)b * NN;
    const float* pc  = p_cls   + (size_t)b * NN * CC;
    const float* pcf = p_conf  + (size_t)b * NN;

    __shared__ double l_cost[KK][S_SL];   // rank-1 exact f64
    __shared__ int    l_col[KK][S_SL];    // rank-1 column
    __shared__ int    l_col2[KK][S_SL];   // rank-2 column (lazy)
    __shared__ double l_bnd[KK][S_SL];    // rank-2 floored f32 - margin (bound for slot2 AND hidden)
    __shared__ double gfs[KK], gfe[KK];
    __shared__ int    gcls[KK], gpres[KK];

    // ---- Phase 0: gt load + clean ----
    if (tid < KK) {
        float f0 = gt[((size_t)b * KK + tid) * 3 + 0];
        float f1 = gt[((size_t)b * KK + tid) * 3 + 1];
        float f2 = gt[((size_t)b * KK + tid) * 3 + 2];
        int pres = !(isnan(f0) || isnan(f1) || isnan(f2));
        if (isnan(f0)) f0 = 0.0f;
        if (isnan(f1)) f1 = 0.0f;
        if (isnan(f2)) f2 = 0.0f;
        int ci = (int)f2; ci = ci < 0 ? 0 : (ci > CC - 1 ? CC - 1 : ci);
        gfs[tid] = (double)f0; gfe[tid] = (double)f1;
        gcls[tid] = ci; gpres[tid] = pres;
    }
    __syncthreads();

    // ---- Phase 1: f64 eval of the K*64 RANK-1 candidates only (rank-2 stays a bound) ----
    for (int idx = tid; idx < KK * S_SL; idx += TPM) {
        const int r = idx >> 6, sl = idx & 63;
        uint2 pk = cand[((size_t)b * S_SL + sl) * KK + r];
        int c = sl * SLICE + (int)(pk.x & CMASK);
        if (c < 0 || c >= NN) c = 0;   // cannot trigger; OOB-crash guard only
        l_cost[r][sl] = eval64(ps, pe, pc, gfs[r], gfe[r], gcls[r], gpres[r], c);
        l_col[r][sl]  = c;
        l_col2[r][sl] = sl * SLICE + (int)(pk.y & CMASK);
        l_bnd[r][sl]  = (double)__uint_as_float(pk.y & VMASK) - BND_MARGIN;
    }
    __syncthreads();
    if (wv != 0) return;   // wave 0 owns the greedy (LDS persists)

    // ---- Phase 2: greedy matching; lane j owns slice j entirely ----
    // slot0: exact (v0,c0). slot1: column c1 with lazy value (bnd until e2 bit set -> v2 exact).
    double v0[KK], v2[KK], bnd[KK]; int c0[KK], c1[KK];
    unsigned e2bits = 0;
    #pragma unroll
    for (int r = 0; r < KK; r++) {
        v0[r] = l_cost[r][j]; c0[r] = l_col[r][j];
        c1[r] = l_col2[r][j]; bnd[r] = l_bnd[r][j]; v2[r] = bnd[r];
    }

    unsigned act = (1u << KK) - 1;
    int cons[KK], prow[KK], pcolv[KK], pvalid[KK];
    #pragma unroll
    for (int r = 0; r < KK; r++) { cons[r] = -1; pvalid[r] = 0; prow[r] = 0; pcolv[r] = 0; }

    for (int step = 0; step < KK; step++) {
        double bv = DBL_MAX; int brow = 0x7fffffff, bcol = 0x7fffffff;
        // guard: every resolution permanently realifies a slot or slice; terminates provably.
        for (int guard = 0; guard < 256; guard++) {
            double lv = DBL_MAX; int lr = 0x7fffffff, lc = 0x7fffffff;
            #pragma unroll
            for (int r = 0; r < KK; r++) {
                if (!((act >> r) & 1)) continue;
                const bool a0 = (c0[r] >= 0), a1 = (c1[r] >= 0);
                const bool ev = (e2bits >> r) & 1;
                double va = DBL_MAX; int ca = 0x7fffffff;
                if (a0) { va = v0[r]; ca = c0[r]; }
                if (a1) {
                    const double vb = ev ? v2[r] : bnd[r];
                    const int    cb2 = ev ? c1[r] : (-2 - 2 * j);   // lazy tag (kind 0)
                    if (vb < va || (vb == va && cb2 < ca)) { va = vb; ca = cb2; }
                }
                if (!a0 && !a1 && bnd[r] < DBL_MAX) { va = bnd[r]; ca = -3 - 2 * j; }  // hidden tag
                if (va < lv || (va == lv && (r < lr || (r == lr && ca < lc)))) {
                    lv = va; lr = r; lc = ca;
                }
            }
            #pragma unroll
            for (int off = 1; off < 64; off <<= 1) {
                const double ov = __shfl_xor(lv, off, 64);
                const int   orr = __shfl_xor(lr, off, 64);
                const int   oc  = __shfl_xor(lc, off, 64);
                if (ov < lv || (ov == lv && (orr < lr || (orr == lr && oc < lc)))) {
                    lv = ov; lr = orr; lc = oc;
                }
            }
            bv = lv; brow = lr; bcol = lc;
            if (bcol >= 0 || bv == DBL_MAX) break;   // real winner (or nothing left)

            const int idxn = -bcol - 2;
            const int ss = idxn >> 1, kind = idxn & 1;

            if (kind == 0) {
                // lazy rank-2 won -> single exact eval of that slot, then retry
                #pragma unroll
                for (int r = 0; r < KK; r++) {
                    if (r != brow) continue;
                    int cc = __shfl(c1[r], ss, 64);
                    if (cc < 0 || cc >= NN) cc = 0;
                    const double vv = eval64(ps, pe, pc, gfs[r], gfe[r], gcls[r], gpres[r], cc);
                    if (j == ss) { v2[r] = vv; e2bits |= (1u << r); }
                }
                continue;
            }

            // hidden bound won -> exact top-2 rescan of (row brow, slice ss). Rare.
            const float ffs = (float)gfs[brow], ffe = (float)gfe[brow];
            const int   cb  = gcls[brow], pb = gpres[brow];
            const float m0b = -2.0f * ffs, m1b = -2.0f * ffe;
            const float ckb = fmaf(ffs, ffs, ffe * ffe) + (pb ? 0.0f : (float)VLARGE);
            unsigned q1 = KEY32_MAX, q2 = KEY32_MAX;
            const int cbase = ss * SLICE;
            for (int t = j; t < SLICE; t += 64) {
                const int n = cbase + t;
                bool used = false;
                #pragma unroll
                for (int u = 0; u < KK; u++) used |= (cons[u] == n);
                float s, e, u0, u1;
                colterms(ps[n], pe[n], pc[2 * n], pc[2 * n + 1], s, e, u0, u1);
                const float cst = rowcost(s, e, u0, u1, m0b, m1b, ckb, cb);
                const unsigned kk = used ? KEY32_MAX : ((__float_as_uint(cst) & VMASK) | (unsigned)t);
                if (kk < q2) { if (kk < q1) { q2 = q1; q1 = kk; } else { q2 = kk; } }
            }
            #pragma unroll
            for (int off = 1; off < 64; off <<= 1) {
                const unsigned o1 = __shfl_xor(q1, off, 64);
                const unsigned o2 = __shfl_xor(q2, off, 64);
                merge2_32(q1, q2, o1, o2);
            }
            int cA = cbase + (int)(q1 & CMASK);
            int cB = cbase + (int)(q2 & CMASK);
            if (cA < 0 || cA >= NN) cA = 0;
            if (cB < 0 || cB >= NN) cB = 0;
            const double vA = (q1 == KEY32_MAX) ? DBL_MAX
                : eval64(ps, pe, pc, gfs[brow], gfe[brow], cb, pb, cA);
            const double vB = (q2 == KEY32_MAX) ? DBL_MAX
                : eval64(ps, pe, pc, gfs[brow], gfe[brow], cb, pb, cB);
            const double nb = (q2 == KEY32_MAX) ? DBL_MAX
                : (double)__uint_as_float(q2 & VMASK) - BND_MARGIN;
            #pragma unroll
            for (int r = 0; r < KK; r++) {
                if (r != brow) continue;
                if (j == ss) {
                    v0[r] = vA; c0[r] = (q1 == KEY32_MAX) ? -1 : cA;
                    v2[r] = vB; c1[r] = (q2 == KEY32_MAX) ? -1 : cB;
                    e2bits |= (1u << r);           // rank-2 now exact
                    bnd[r] = nb;                   // hidden >= rescan 2nd - margin
                }
            }
        }

        prow[step]   = brow;
        pcolv[step]  = bcol;
        pvalid[step] = (bv < VLARGE * 0.5) && (bcol >= 0) && (brow < KK);
        cons[step]   = (bcol >= 0) ? bcol : -1;
        if (brow < KK) act &= ~(1u << brow);
        else break;                          // nothing left at all

        if (bcol >= 0) {
            #pragma unroll
            for (int r = 0; r < KK; r++) {
                if (c0[r] == bcol) { c0[r] = -1; v0[r] = DBL_MAX; }
                if (c1[r] == bcol) { c1[r] = -1; }
            }
        }
    }

    // ---- Phase 3: losses, one pick per lane ----
    double loss = 0.0, m = 0.0;
    if (j < KK && pvalid[j]) {
        const int r = prow[j], cidx = pcolv[j];
        const double ss = dsig(ps[cidx]);
        const double se = dsig(pe[cidx]);
        const double gs = gfs[r], ge = gfe[r];
        const double d0 = ss - gs, d1 = se - ge;
        double acc = d0 * d0 + d1 * d1;

        const double l0 = (double)pc[2 * cidx];
        const double l1 = (double)pc[2 * cidx + 1];
        const double y0 = (gcls[r] == 0) ? 1.0 : 0.0;
        const double y1 = 1.0 - y0;
        acc += y0 * dsoftplus(-l0) + (1.0 - y0) * dsoftplus(l0)
             + y1 * dsoftplus(-l1) + (1.0 - y1) * dsoftplus(l1);

        const double a1 = fmin(ss, se), b1 = fmax(ss, se);
        const double a2 = fmin(gs, ge), b2 = fmax(gs, ge);
        const double inter = fmax(0.0, fmin(b1, b2) - fmax(a1, a2));
        const double uni   = fmax(1e-8, fmax(b1, b2) - fmin(a1, a2));
        const double iou   = inter / uni;
        const double dcf   = dsig(pcf[cidx]) - iou;
        acc += dcf * dcf;
        loss = acc; m = 1.0;
    }
    #pragma unroll
    for (int off = 1; off < 64; off <<= 1) {
        loss += __shfl_xor(loss, off, 64);
        m    += __shfl_xor(m, off, 64);
    }
    if (j == 0) { partials[b * 2 + 0] = loss; partials[b * 2 + 1] = m; }

    // ---- Phase 4: fused finalize — last block reduces all partials (r8/r10-validated) ----
    __threadfence();
    int ticket = 0;
    if (j == 0) ticket = (int)atomicAdd(counter, 1u);
    ticket = __shfl(ticket, 0, 64);
    if (ticket == BB - 1) {
        __threadfence();
        for (int i = j; i < out_size; i += 64) out[i] = 0.0f;
        double s = partials[j * 2 + 0];
        double mm = partials[j * 2 + 1];
        #pragma unroll
        for (int off = 1; off < 64; off <<= 1) {
            s  += __shfl_xor(s, off, 64);
            mm += __shfl_xor(mm, off, 64);
        }
        if (j == 0) {
            const double total = s / (mm + 1e-8);
            out[0] = (float)(mm > 0.0 ? total : 0.0);
        }
    }
}

extern "C" void kernel_launch(void* const* d_in, const int* in_sizes, int n_in,
                              void* d_out, int out_size, void* d_ws, size_t ws_size,
                              hipStream_t stream) {
    const float* p_start = (const float*)d_in[0];  // (B, N)
    const float* p_end   = (const float*)d_in[1];  // (B, N)
    const float* p_cls   = (const float*)d_in[2];  // (B, N, C)
    const float* p_conf  = (const float*)d_in[3];  // (B, N)
    const float* gt      = (const float*)d_in[4];  // (B, K, 3)

    const size_t cand_bytes = (size_t)BB * S_SL * KK * sizeof(uint2);   // 320 KiB
    const size_t part_bytes = (size_t)BB * 2 * sizeof(double);          // 1 KiB
    uint2*        cand     = (uint2*)d_ws;
    double*       partials = (double*)((char*)d_ws + cand_bytes);
    unsigned int* counter  = (unsigned int*)((char*)d_ws + cand_bytes + part_bytes);

    scan_kernel<<<dim3(S_SL, BB), 64, 0, stream>>>(p_start, p_end, p_cls, gt, cand, counter);
    match_kernel<<<BB, TPM, 0, stream>>>(p_start, p_end, p_cls, p_conf, gt, cand,
                                         partials, counter, (float*)d_out, out_size);
}